// Round 10
// baseline (209.103 us; speedup 1.0000x reference)
//
#include <hip/hip_runtime.h>

#define NS 65536
#define DD 32
#define RR 128
#define PR4 25   // float4s per rule in PRM: [0..7]=w, [8..15]=-a*w, [16..23]=ck, [24].x=bias

__global__ void anfis_pre(const float* __restrict__ A, const float* __restrict__ B,
                          const float* __restrict__ C, float4* __restrict__ PRM) {
    int i = blockIdx.x * 256 + threadIdx.x;     // i = r*8 + q
    if (i < RR * 8) {
        int r = i >> 3, q = i & 7;
        float4 va = *(const float4*)(A + r * DD + q * 4);
        float4 vb = *(const float4*)(B + r * DD + q * 4);
        float w0 = 0.8493218003f / fmaxf(vb.x, 1e-8f);   // sqrt(log2e/2)/clamp(b)
        float w1 = 0.8493218003f / fmaxf(vb.y, 1e-8f);
        float w2 = 0.8493218003f / fmaxf(vb.z, 1e-8f);
        float w3 = 0.8493218003f / fmaxf(vb.w, 1e-8f);
        float4* pr = PRM + r * PR4;
        pr[q]      = make_float4(w0, w1, w2, w3);
        pr[8 + q]  = make_float4(-va.x * w0, -va.y * w1, -va.z * w2, -va.w * w3);
        pr[16 + q] = make_float4(C[r*33+4*q], C[r*33+4*q+1], C[r*33+4*q+2], C[r*33+4*q+3]);
        if (q == 0) pr[24] = make_float4(C[r * 33 + 32], 0.f, 0.f, 0.f);
    }
}

#define Q4(xv, wv, nv, kv) { float t; \
    t = fmaf(xv.x, wv.x, nv.x); s0 = fmaf(t, t, s0); r0 = fmaf(xv.x, kv.x, r0); \
    t = fmaf(xv.y, wv.y, nv.y); s1 = fmaf(t, t, s1); r1 = fmaf(xv.y, kv.y, r1); \
    t = fmaf(xv.z, wv.z, nv.z); s2 = fmaf(t, t, s2); r2 = fmaf(xv.z, kv.z, r2); \
    t = fmaf(xv.w, wv.w, nv.w); s3 = fmaf(t, t, s3); r3 = fmaf(xv.w, kv.w, r3); }

// Block = 128 threads = 2 independent waves; LANE = SAMPLE. Each thread: its x row in
// 8 named float4s (32 VGPRs, loaded once); ssum/dot are per-lane accumulators (no
// cross-lane reduction, no barriers at all). Params stream per rule as wave-uniform
// VECTOR b128 loads (VGPR-tainted base so they can't become s_loads), double-buffered
// at rule granularity in two banks of 25 named float4s -> latency fully covered by
// the previous rule's 96 FMAs. Strengths staged per-wave in [64][17] LDS, flushed
// every 16 rules; norm = re-read str from L2 after vmcnt(0).
__global__ __launch_bounds__(128, 1) void anfis_main(
    const float* __restrict__ X, const float4* __restrict__ PRM,
    float* __restrict__ out_pred, float* __restrict__ out_str,
    float* __restrict__ out_norm)
{
    __shared__ float SBUF[2][64 * 17];
    __shared__ float scl[128];

    const int tid  = threadIdx.x;
    const int w    = tid >> 6;
    const int lane = tid & 63;
    const int nb   = blockIdx.x * 128;
    const int n    = nb + w * 64 + lane;        // this thread's sample

    const float4* xp = (const float4*)(X + (size_t)n * DD);
    float4 x0 = xp[0], x1 = xp[1], x2 = xp[2], x3 = xp[3];
    float4 x4 = xp[4], x5 = xp[5], x6 = xp[6], x7 = xp[7];

    int vz; asm("v_mov_b32 %0, 0" : "=v"(vz));  // opaque 0: forces vector param loads
    const float4* P = PRM + vz;

    float* sb = &SBUF[w][0];                    // wave-private [64][17]
    float ssum = 0.f, dot = 0.f;

    float4 wa0,wa1,wa2,wa3,wa4,wa5,wa6,wa7, na0,na1,na2,na3,na4,na5,na6,na7,
           ka0,ka1,ka2,ka3,ka4,ka5,ka6,ka7, ba;
    float4 wb0,wb1,wb2,wb3,wb4,wb5,wb6,wb7, nb0,nb1,nb2,nb3,nb4,nb5,nb6,nb7,
           kb0,kb1,kb2,kb3,kb4,kb5,kb6,kb7, bb;

#define LOADP(s, rr) { const float4* p_ = P + (rr) * PR4; \
    w##s##0=p_[0]; w##s##1=p_[1]; w##s##2=p_[2]; w##s##3=p_[3]; \
    w##s##4=p_[4]; w##s##5=p_[5]; w##s##6=p_[6]; w##s##7=p_[7]; \
    n##s##0=p_[8]; n##s##1=p_[9]; n##s##2=p_[10]; n##s##3=p_[11]; \
    n##s##4=p_[12]; n##s##5=p_[13]; n##s##6=p_[14]; n##s##7=p_[15]; \
    k##s##0=p_[16]; k##s##1=p_[17]; k##s##2=p_[18]; k##s##3=p_[19]; \
    k##s##4=p_[20]; k##s##5=p_[21]; k##s##6=p_[22]; k##s##7=p_[23]; \
    b##s=p_[24]; }

#define COMP(s, rr) { \
    float s0=0.f, s1=0.f, s2=0.f, s3=0.f; \
    float r0=b##s.x, r1=0.f, r2=0.f, r3=0.f; \
    Q4(x0, w##s##0, n##s##0, k##s##0) Q4(x1, w##s##1, n##s##1, k##s##1) \
    Q4(x2, w##s##2, n##s##2, k##s##2) Q4(x3, w##s##3, n##s##3, k##s##3) \
    Q4(x4, w##s##4, n##s##4, k##s##4) Q4(x5, w##s##5, n##s##5, k##s##5) \
    Q4(x6, w##s##6, n##s##6, k##s##6) Q4(x7, w##s##7, n##s##7, k##s##7) \
    float st = __builtin_amdgcn_exp2f(-((s0 + s1) + (s2 + s3))); \
    float ro = (r0 + r1) + (r2 + r3); \
    sb[lane * 17 + ((rr) & 15)] = st; \
    ssum += st; dot = fmaf(st, ro, dot); }

    LOADP(a, 0)
    #pragma unroll 1
    for (int i = 0; i < 64; ++i) {
        const int r0i = 2 * i;
        LOADP(b, r0i + 1)            // prefetch rule r+1 into bank B
        COMP(a, r0i)                 // 96 FMAs cover the load latency
        LOADP(a, (r0i + 2) & 127)    // prefetch rule r+2 into bank A
        COMP(b, r0i + 1)
        if ((i & 7) == 7) {          // flush 16-rule group g (wave-private, no barrier)
            const int g = i >> 3;
            #pragma unroll
            for (int it = 0; it < 4; ++it) {
                int f = it * 64 + lane;
                int row = f >> 2, c4 = f & 3;
                float4 v = *(const float4*)&sb[row * 17 + c4 * 4];
                *(float4*)(out_str + (size_t)(nb + w * 64 + row) * RR + g * 16 + c4 * 4) = v;
            }
        }
    }

    float sc = 1.f / (ssum + 1e-8f);
    out_pred[n]        = dot * sc;              // coalesced 256 B per wave
    scl[w * 64 + lane] = sc;
    asm volatile("s_waitcnt vmcnt(0) lgkmcnt(0)" ::: "memory");  // drain str stores

    // normalized = re-read str (L2-hot, fully coalesced 512 B rows) x per-row scale
    const float* strb = out_str  + (size_t)(nb + w * 64) * RR;
    float*       nrmb = out_norm + (size_t)(nb + w * 64) * RR;
    #pragma unroll 8
    for (int it = 0; it < 32; ++it) {
        int f = it * 64 + lane;
        int row = f >> 5, c = f & 31;
        float4 v = *(const float4*)(strb + (size_t)row * RR + c * 4);
        float s2 = scl[w * 64 + row];
        *(float4*)(nrmb + (size_t)row * RR + c * 4) =
            make_float4(v.x * s2, v.y * s2, v.z * s2, v.w * s2);
    }
}

extern "C" void kernel_launch(void* const* d_in, const int* in_sizes, int n_in,
                              void* d_out, int out_size, void* d_ws, size_t ws_size,
                              hipStream_t stream) {
    const float* X = (const float*)d_in[0];
    const float* A = (const float*)d_in[1];
    const float* B = (const float*)d_in[2];
    const float* C = (const float*)d_in[3];

    float4* PRM = (float4*)d_ws;                // 128 rules x 25 float4 = 51.2 KB

    float* pred = (float*)d_out;
    float* str  = pred + NS;
    float* nrm  = str + (size_t)NS * RR;

    anfis_pre<<<dim3(4), dim3(256), 0, stream>>>(A, B, C, PRM);
    anfis_main<<<dim3(NS / 128), dim3(128), 0, stream>>>(X, PRM, pred, str, nrm);
}

// Round 11
// 112.098 us; speedup vs baseline: 1.8654x; 1.8654x over previous
//
#include <hip/hip_runtime.h>

#define NS 65536
#define DD 32
#define RR 128
#define RST 112   // rule stride in PP (floats): [a16|w16|ck16] x2 halves + bias + pad

// Pack per rule: half h at h*48: [a(16) | w(16) | ck(16)]; bias at [96]. w has the
// log2e/2 clamp fold. 112-float stride keeps s_load_dwordx16 offsets 16-dword aligned.
__global__ void anfis_pre(const float* __restrict__ A, const float* __restrict__ B,
                          const float* __restrict__ C, float* __restrict__ PP) {
    int i = blockIdx.x * 256 + threadIdx.x;     // i = r*8 + q  (q = dim quad)
    if (i < RR * 8) {
        int r = i >> 3, q = i & 7;
        float4 va = *(const float4*)(A + r * DD + q * 4);
        float4 vb = *(const float4*)(B + r * DD + q * 4);
        float w0 = 0.8493218003f / fmaxf(vb.x, 1e-8f);   // sqrt(log2e/2)/clamp(b)
        float w1 = 0.8493218003f / fmaxf(vb.y, 1e-8f);
        float w2 = 0.8493218003f / fmaxf(vb.z, 1e-8f);
        float w3 = 0.8493218003f / fmaxf(vb.w, 1e-8f);
        int h = q >> 2, j = q & 3;
        float* base = PP + r * RST + h * 48;
        *(float4*)(base + j * 4)      = va;
        *(float4*)(base + 16 + j * 4) = make_float4(w0, w1, w2, w3);
        *(float4*)(base + 32 + j * 4) = make_float4(C[r*33+4*q], C[r*33+4*q+1],
                                                    C[r*33+4*q+2], C[r*33+4*q+3]);
        if (q == 0) PP[r * RST + 96] = C[r * 33 + 32];
    }
}

// Block = 256 threads = 4 waves; LANE = SAMPLE (64/block, same for all waves);
// wave w owns rules [32w, 32w+32). x row: 8 named float4s (32 VGPRs, loaded once).
// Params: readfirstlane-forced SGPR offset => s_load_dwordx16 into SGPRs (K$/L2-
// resident, wave-shared). Inner 4 ops/elem, each with exactly 1 SGPR operand.
// ssum/dot are per-lane accumulators; one barrier; fused coalesced str+norm flush.
__global__ __launch_bounds__(256, 4) void anfis_main(
    const float* __restrict__ X, const float* __restrict__ PP,
    float* __restrict__ out_pred, float* __restrict__ out_str,
    float* __restrict__ out_norm)
{
    __shared__ float SBUF[4][64 * 33];   // 33.8 KB strengths, [wave][lane*33+rule]
    __shared__ float pS[4][64];
    __shared__ float pD[4][64];
    __shared__ float scl[64];

    const int tid  = threadIdx.x;
    const int w    = tid >> 6;
    const int lane = tid & 63;
    const int n    = blockIdx.x * 64 + lane;     // this thread's sample

    const float4* xp = (const float4*)(X + (size_t)n * DD);
    float4 q0 = xp[0], q1 = xp[1], q2 = xp[2], q3 = xp[3];
    float4 q4 = xp[4], q5 = xp[5], q6 = xp[6], q7 = xp[7];

    float ssum = 0.f, dot = 0.f;

#define QUAD(xv, base, j) { float t; \
    t = (xv.x - pr[(base)+4*(j)+0]) * pr[(base)+16+4*(j)+0]; s0 = fmaf(t, t, s0); \
    r0 = fmaf(xv.x, pr[(base)+32+4*(j)+0], r0); \
    t = (xv.y - pr[(base)+4*(j)+1]) * pr[(base)+16+4*(j)+1]; s1 = fmaf(t, t, s1); \
    r1 = fmaf(xv.y, pr[(base)+32+4*(j)+1], r1); \
    t = (xv.z - pr[(base)+4*(j)+2]) * pr[(base)+16+4*(j)+2]; s2 = fmaf(t, t, s2); \
    r2 = fmaf(xv.z, pr[(base)+32+4*(j)+2], r2); \
    t = (xv.w - pr[(base)+4*(j)+3]) * pr[(base)+16+4*(j)+3]; s3 = fmaf(t, t, s3); \
    r3 = fmaf(xv.w, pr[(base)+32+4*(j)+3], r3); }

    #pragma unroll 1
    for (int i = 0; i < 32; ++i) {
        // Force SGPR address: rule offset via readfirstlane => s_load_dwordx16 params
        const int off = __builtin_amdgcn_readfirstlane((w * 32 + i) * RST);
        const float* pr = PP + off;
        float s0 = 0.f, s1 = 0.f, s2 = 0.f, s3 = 0.f;
        float r0 = pr[96], r1 = 0.f, r2 = 0.f, r3 = 0.f;
        QUAD(q0, 0, 0) QUAD(q1, 0, 1) QUAD(q2, 0, 2) QUAD(q3, 0, 3)
        QUAD(q4, 48, 0) QUAD(q5, 48, 1) QUAD(q6, 48, 2) QUAD(q7, 48, 3)
        float st = __builtin_amdgcn_exp2f(-((s0 + s1) + (s2 + s3)));
        float ro = (r0 + r1) + (r2 + r3);
        SBUF[w][lane * 33 + i] = st;      // bank (lane+i)%32: 2-way = free
        ssum += st;
        dot = fmaf(st, ro, dot);
    }
#undef QUAD

    pS[w][lane] = ssum;
    pD[w][lane] = dot;
    __syncthreads();

    if (w == 0) {
        float ss = (pS[0][lane] + pS[1][lane]) + (pS[2][lane] + pS[3][lane]);
        float dd = (pD[0][lane] + pD[1][lane]) + (pD[2][lane] + pD[3][lane]);
        float sc = 1.0f / (ss + 1e-8f);
        out_pred[n] = dd * sc;
        scl[lane] = sc;
    }
    __syncthreads();

    // ---- fused str+norm flush: 8 iters, each instr covers 8 rows x 128 B ----
    const int a8 = lane >> 3;   // row-in-group
    const int k8 = lane & 7;    // float4 col within the wave's 32-rule quarter
    #pragma unroll
    for (int it = 0; it < 8; ++it) {
        int si = it * 8 + a8;
        const float* row = &SBUF[w][si * 33 + k8 * 4];
        float4 v = make_float4(row[0], row[1], row[2], row[3]);
        float sc = scl[si];
        size_t base = (size_t)(blockIdx.x * 64 + si) * RR + w * 32 + k8 * 4;
        *(float4*)(out_str  + base) = v;
        *(float4*)(out_norm + base) = make_float4(v.x * sc, v.y * sc, v.z * sc, v.w * sc);
    }
}

extern "C" void kernel_launch(void* const* d_in, const int* in_sizes, int n_in,
                              void* d_out, int out_size, void* d_ws, size_t ws_size,
                              hipStream_t stream) {
    const float* X = (const float*)d_in[0];
    const float* A = (const float*)d_in[1];
    const float* B = (const float*)d_in[2];
    const float* C = (const float*)d_in[3];

    float* PP = (float*)d_ws;                   // 128 x 112 floats = 57.3 KB

    float* pred = (float*)d_out;
    float* str  = pred + NS;
    float* nrm  = str + (size_t)NS * RR;

    anfis_pre<<<dim3(4), dim3(256), 0, stream>>>(A, B, C, PP);
    anfis_main<<<dim3(NS / 64), dim3(256), 0, stream>>>(X, PP, pred, str, nrm);
}